// Round 14
// baseline (184.013 us; speedup 1.0000x reference)
//
#include <hip/hip_runtime.h>
#include <stdint.h>

#define BSz 4096   // B*S tokens
#define Ddim 1024
#define Fdim 4096
#define Edim 4
#define Rdim 4

typedef __attribute__((ext_vector_type(8))) short bf16x8;
typedef __attribute__((ext_vector_type(4))) float f32x4;

__device__ __forceinline__ unsigned short f2bf(float f) {
  union { float f; uint32_t u; } c; c.f = f;
  return (unsigned short)((c.u + 0x7fffu + ((c.u >> 16) & 1u)) >> 16);
}

// -------- prep mega-kernel: router+cvt(x) (blocks 0..BSz-1) ||
//          Wi/Wo fp32->bf16 (blocks BSz..BSz+8191) in ONE launch ----------
__global__ __launch_bounds__(256) void prep_kernel(const float* __restrict__ x,
                                                   const float* __restrict__ Wg,
                                                   const float* __restrict__ bg,
                                                   const float* __restrict__ Aw,
                                                   const float* __restrict__ Wi,
                                                   const float* __restrict__ Wo,
                                                   unsigned short* __restrict__ xb,
                                                   unsigned short* __restrict__ wib,
                                                   unsigned short* __restrict__ wob,
                                                   float* __restrict__ meta) {
  const int b = blockIdx.x;
  if (b >= BSz) {
    // weight conversion: 8192 blocks x 256 thr x 1 float4 over 2 x 1M float4
    const int n4 = Fdim * Ddim / 4;                    // 1M per tensor
    int i = (b - BSz) * 256 + threadIdx.x;             // 0 .. 2n4-1
    const float* src = (i < n4) ? Wi : Wo;
    unsigned short* dst = (i < n4) ? wib : wob;
    if (i >= n4) i -= n4;
    float4 v = ((const float4*)src)[i];
    ushort4 o;
    o.x = f2bf(v.x); o.y = f2bf(v.y); o.z = f2bf(v.z); o.w = f2bf(v.w);
    ((ushort4*)dst)[i] = o;
    return;
  }
  // ---- router + cvt(x) for token t = b ----
  __shared__ float xs[Ddim];
  __shared__ float dots[Edim + Edim * Rdim];
  const int t = b;
  {
    const int i = threadIdx.x;                         // 256 thr x float4 = 1024
    float4 v = ((const float4*)(x + (size_t)t * Ddim))[i];
    ((float4*)xs)[i] = v;
    ushort4 o;
    o.x = f2bf(v.x); o.y = f2bf(v.y); o.z = f2bf(v.z); o.w = f2bf(v.w);
    ((ushort4*)(xb + (size_t)t * Ddim))[i] = o;
  }
  __syncthreads();
  const int wave = threadIdx.x >> 6, lane = threadIdx.x & 63;
  for (int d = wave * 5; d < wave * 5 + 5; ++d) {
    const float* wrow = (d < Edim) ? (Wg + (size_t)d * Ddim)
                                   : (Aw + (size_t)(d - Edim) * Ddim);
    float s = 0.f;
    for (int i = lane; i < Ddim; i += 64) s += xs[i] * wrow[i];
    for (int off = 32; off; off >>= 1) s += __shfl_down(s, off);
    if (lane == 0) dots[d] = s;
  }
  __syncthreads();
  if (threadIdx.x == 0) {
    float p[Edim];
    float m = -1e30f;
    for (int e = 0; e < Edim; ++e) { p[e] = dots[e] + bg[e]; m = fmaxf(m, p[e]); }
    float sum = 0.f;
    for (int e = 0; e < Edim; ++e) { p[e] = expf(p[e] - m); sum += p[e]; }
    const float inv = 1.f / sum;
    for (int e = 0; e < Edim; ++e) p[e] *= inv;
    int e0 = 0;
    for (int e = 1; e < Edim; ++e) if (p[e] > p[e0]) e0 = e;
    int e1 = (e0 == 0) ? 1 : 0;
    for (int e = 0; e < Edim; ++e) if (e != e0 && p[e] > p[e1]) e1 = e;
    float* mt = meta + (size_t)t * 16;
    mt[0] = (float)e0; mt[1] = (float)e1; mt[2] = p[e0]; mt[3] = p[e1];
    for (int r = 0; r < Rdim; ++r) {
      mt[4 + r] = dots[Edim + e0 * Rdim + r];
      mt[8 + r] = dots[Edim + e1 * Rdim + r];
    }
    mt[12] = 0.f; mt[13] = 0.f; mt[14] = 0.f; mt[15] = 0.f;
  }
}

// ------------- GEMM1: 256x128 tile, fused MoE epilogue ------------------
// g[M=4096, F=4096] from xb[M,1024] * wib[F,1024]^T. 8 waves (4M x 2N),
// BK=64, single-buffered 48KB LDS (A 32KB + B 16KB), plain __syncthreads,
// 2 blocks/CU (16 waves/CU, same residency as R13's 4x128^2).
// Staged DMA bytes 384MB vs 512MB at 128^2 (A amortized over 2x output).
// XOR chunk swizzle (chunk ^ row&7) via pre-swizzled source + swizzled read.
// Also zeroes zbuf (split-K base for GEMM2) before the K-loop.
__global__ __launch_bounds__(512, 2)
void gemm1_w(const unsigned short* __restrict__ Ag,
             const unsigned short* __restrict__ Bg,
             const float* __restrict__ meta,
             const float* __restrict__ B2,
             unsigned short* __restrict__ outg,
             float* __restrict__ zbuf) {
  constexpr int K = Ddim, BK = 64;
  __shared__ __align__(16) unsigned short sA[256 * BK];   // 32 KB
  __shared__ __align__(16) unsigned short sB[128 * BK];   // 16 KB

  const int tid = threadIdx.x;
  const int lane = tid & 63;
  const int wave = tid >> 6;            // 0..7
  const int wr = wave >> 1, wc = wave & 1;   // 4 x 2 wave grid of 64x64
  const int l16 = lane & 15, lhi = lane >> 4;

  // XCD-aware bijective swizzle (nwg = 512, % 8 == 0)
  const int nwg = gridDim.x * gridDim.y;
  const int lin = blockIdx.y * gridDim.x + blockIdx.x;
  const int cpx = nwg >> 3;
  const int swz = (lin & 7) * cpx + (lin >> 3);
  const int bx = swz % gridDim.x, by = swz / gridDim.x;
  const int bm = by * 256, bn = bx * 128;

  // fused zero of split-K target: 512 blocks x 512 thr x 4 float4 = 16 MB
  {
    const float4 z4 = make_float4(0.f, 0.f, 0.f, 0.f);
#pragma unroll
    for (int zz = 0; zz < 4; ++zz)
      ((float4*)zbuf)[(size_t)lin * 2048 + zz * 512 + tid] = z4;
  }

  f32x4 acc[4][4] = {};

  // staging: 512 thr x 16B = 8KB/round. A: 4 rounds (256 rows), B: 2 rounds.
  const int srow = tid >> 3;                                  // 0..63
  const int scol = ((tid & 7) ^ (srow & 7)) * 8;              // swizzled col
  const int ldst = tid * 8;
  const int xr = l16 & 7;                                     // read-side XOR

  for (int kt = 0; kt < K / BK; ++kt) {
    const int kof = kt * BK;
#pragma unroll
    for (int rr = 0; rr < 4; ++rr)
      __builtin_amdgcn_global_load_lds(
          (const __attribute__((address_space(1))) void*)(Ag + (size_t)(bm + srow + rr * 64) * K + kof + scol),
          (__attribute__((address_space(3))) void*)(sA + ldst + rr * 4096), 16, 0, 0);
#pragma unroll
    for (int rr = 0; rr < 2; ++rr)
      __builtin_amdgcn_global_load_lds(
          (const __attribute__((address_space(1))) void*)(Bg + (size_t)(bn + srow + rr * 64) * K + kof + scol),
          (__attribute__((address_space(3))) void*)(sB + ldst + rr * 4096), 16, 0, 0);
    __syncthreads();
#pragma unroll
    for (int kk = 0; kk < 2; ++kk) {
      bf16x8 af[4], bfv[4];
#pragma unroll
      for (int i = 0; i < 4; ++i) {
        af[i] = *(const bf16x8*)(sA + (wr * 64 + i * 16 + l16) * BK + (((kk * 4 + lhi) ^ xr) * 8));
        bfv[i] = *(const bf16x8*)(sB + (wc * 64 + i * 16 + l16) * BK + (((kk * 4 + lhi) ^ xr) * 8));
      }
#pragma unroll
      for (int i = 0; i < 4; ++i)
#pragma unroll
        for (int j = 0; j < 4; ++j)
          acc[i][j] = __builtin_amdgcn_mfma_f32_16x16x32_bf16(af[i], bfv[j], acc[i][j], 0, 0, 0);
    }
    __syncthreads();
  }

  // fused MoE epilogue, two 128-row passes repacked through sA (32 KB).
#pragma unroll
  for (int half = 0; half < 2; ++half) {
    if ((wr >> 1) == half) {
#pragma unroll
      for (int mi = 0; mi < 4; ++mi) {
#pragma unroll
        for (int r = 0; r < 4; ++r) {
          const int rowl = wr * 64 + mi * 16 + lhi * 4 + r;   // 0..255
          const int row = bm + rowl;
          const float* mt = meta + (size_t)row * 16;
          const int e0 = (int)mt[0], e1 = (int)mt[1];
          const float w0 = mt[2], w1 = mt[3];
          const float4 l0 = *(const float4*)(mt + 4);
          const float4 l1 = *(const float4*)(mt + 8);
#pragma unroll
          for (int ni = 0; ni < 4; ++ni) {
            const int coll = wc * 64 + ni * 16 + l16;
            const int f = bn + coll;
            const float4 b0 = *(const float4*)(B2 + ((size_t)e0 * Fdim + f) * Rdim);
            const float4 b1 = *(const float4*)(B2 + ((size_t)e1 * Fdim + f) * Rdim);
            const float a = acc[mi][ni][r];
            const float lora0 = l0.x * b0.x + l0.y * b0.y + l0.z * b0.z + l0.w * b0.w;
            const float lora1 = l1.x * b1.x + l1.y * b1.y + l1.z * b1.z + l1.w * b1.w;
            const float gv = w0 * fmaxf(a + lora0, 0.f) + w1 * fmaxf(a + lora1, 0.f);
            sA[(rowl - half * 128) * 128 + coll] = f2bf(gv);
          }
        }
      }
    }
    __syncthreads();
    // coalesced copy: 128 rows x 256B; 4 rounds x 512 thr x 16B
#pragma unroll
    for (int rnd = 0; rnd < 4; ++rnd) {
      const int idx = rnd * 512 + tid;            // 0..2047
      const int rowl2 = idx >> 4;                 // 0..127
      const int chk = idx & 15;
      *(bf16x8*)(outg + (size_t)(bm + half * 128 + rowl2) * Fdim + bn + chk * 8) =
          *(const bf16x8*)(sA + rowl2 * 128 + chk * 8);
    }
    __syncthreads();
  }
}

// ---------------- GEMM2: R13-exact (split-K x2, f32 atomics) ----------------
__global__ __launch_bounds__(256, 4)
void gemm2_w(const unsigned short* __restrict__ Ag,
             const unsigned short* __restrict__ Bg,
             int K, int kslice, int Ncols,
             float* __restrict__ outf) {
  constexpr int BK = 64;
  __shared__ __align__(16) unsigned short sA[128 * BK];
  __shared__ __align__(16) unsigned short sB[128 * BK];

  const int tid = threadIdx.x;
  const int lane = tid & 63;
  const int wave = tid >> 6;
  const int wr = wave >> 1, wc = wave & 1;
  const int l16 = lane & 15, lhi = lane >> 4;

  const int nwg = gridDim.x * gridDim.y;
  const int lin = blockIdx.y * gridDim.x + blockIdx.x;
  const int cpx = nwg >> 3;
  const int swz = (lin & 7) * cpx + (lin >> 3);
  const int bx = swz % gridDim.x, by = swz / gridDim.x;
  const int bm = by * 128, bn = bx * 128;
  const int kbase = blockIdx.z * kslice;
  const int NT = kslice / BK;

  f32x4 acc[4][4] = {};

  const int srow = tid >> 3;
  const int scol = ((tid & 7) ^ (srow & 7)) * 8;
  const int ldst = tid * 8;
  const int xr = l16 & 7;

  for (int kt = 0; kt < NT; ++kt) {
    const int kof = kbase + kt * BK;
#pragma unroll
    for (int rr = 0; rr < 4; ++rr)
      __builtin_amdgcn_global_load_lds(
          (const __attribute__((address_space(1))) void*)(Ag + (size_t)(bm + srow + rr * 32) * K + kof + scol),
          (__attribute__((address_space(3))) void*)(sA + ldst + rr * 2048), 16, 0, 0);
#pragma unroll
    for (int rr = 0; rr < 4; ++rr)
      __builtin_amdgcn_global_load_lds(
          (const __attribute__((address_space(1))) void*)(Bg + (size_t)(bn + srow + rr * 32) * K + kof + scol),
          (__attribute__((address_space(3))) void*)(sB + ldst + rr * 2048), 16, 0, 0);
    __syncthreads();
#pragma unroll
    for (int kk = 0; kk < 2; ++kk) {
      bf16x8 af[4], bfv[4];
#pragma unroll
      for (int i = 0; i < 4; ++i) {
        af[i] = *(const bf16x8*)(sA + (wr * 64 + i * 16 + l16) * BK + (((kk * 4 + lhi) ^ xr) * 8));
        bfv[i] = *(const bf16x8*)(sB + (wc * 64 + i * 16 + l16) * BK + (((kk * 4 + lhi) ^ xr) * 8));
      }
#pragma unroll
      for (int i = 0; i < 4; ++i)
#pragma unroll
        for (int j = 0; j < 4; ++j)
          acc[i][j] = __builtin_amdgcn_mfma_f32_16x16x32_bf16(af[i], bfv[j], acc[i][j], 0, 0, 0);
    }
    __syncthreads();
  }

#pragma unroll
  for (int mi = 0; mi < 4; ++mi)
#pragma unroll
    for (int ni = 0; ni < 4; ++ni)
#pragma unroll
      for (int r = 0; r < 4; ++r) {
        const int row = bm + wr * 64 + mi * 16 + lhi * 4 + r;
        const int col = bn + wc * 64 + ni * 16 + l16;
        unsafeAtomicAdd(&outf[(size_t)row * Ncols + col], acc[mi][ni][r]);
      }
}

extern "C" void kernel_launch(void* const* d_in, const int* in_sizes, int n_in,
                              void* d_out, int out_size, void* d_ws, size_t ws_size,
                              hipStream_t stream) {
  const float* x  = (const float*)d_in[0];
  const float* Wg = (const float*)d_in[1];
  const float* bg = (const float*)d_in[2];
  const float* Wi = (const float*)d_in[3];
  const float* Wo = (const float*)d_in[4];
  const float* Aw = (const float*)d_in[5];
  const float* B2 = (const float*)d_in[6];
  float* out = (float*)d_out;

  // workspace layout (bf16 as ushort)
  unsigned short* xb  = (unsigned short*)d_ws;                 // [BSz][Ddim]   8 MB
  unsigned short* wib = xb  + (size_t)BSz  * Ddim;             // [Fdim][Ddim]  8 MB
  unsigned short* wob = wib + (size_t)Fdim * Ddim;             // [Ddim][Fdim]  8 MB
  unsigned short* g   = wob + (size_t)Ddim * Fdim;             // [BSz][Fdim]  32 MB
  float* meta = (float*)(g + (size_t)BSz * Fdim);              // [BSz][16]   256 KB

  // prep: router+cvt(x) (4096 blocks) || Wi/Wo conversion (8192 blocks)
  prep_kernel<<<BSz + 2 * (Fdim * Ddim / 4) / 256, 256, 0, stream>>>(
      x, Wg, bg, Aw, Wi, Wo, xb, wib, wob, meta);

  // GEMM1: g = MoE-epilogue(x * Wi^T); zeroes out. 256x128 tile,
  // grid 32x16 = 512 blocks (2/CU), K=1024
  gemm1_w<<<dim3(Fdim / 128, BSz / 256), 512, 0, stream>>>(
      xb, wib, meta, B2, g, out);

  // GEMM2: out = g * Wo^T, split-K x2, f32 atomics, grid 8x32x2 = 512 blocks
  gemm2_w<<<dim3(Ddim / 128, BSz / 128, 2), 256, 0, stream>>>(
      g, wob, Fdim, Fdim / 2, Ddim, out);
}

// Round 15
// 164.367 us; speedup vs baseline: 1.1195x; 1.1195x over previous
//
#include <hip/hip_runtime.h>
#include <stdint.h>

#define BSz 4096   // B*S tokens
#define Ddim 1024
#define Fdim 4096
#define Edim 4
#define Rdim 4

typedef __attribute__((ext_vector_type(8))) short bf16x8;
typedef __attribute__((ext_vector_type(4))) float f32x4;

__device__ __forceinline__ unsigned short f2bf(float f) {
  union { float f; uint32_t u; } c; c.f = f;
  return (unsigned short)((c.u + 0x7fffu + ((c.u >> 16) & 1u)) >> 16);
}

// -------- prep mega-kernel: router+cvt(x) (blocks 0..BSz-1) ||
//          Wi/Wo fp32->bf16 (blocks BSz..BSz+8191) in ONE launch ----------
__global__ __launch_bounds__(256) void prep_kernel(const float* __restrict__ x,
                                                   const float* __restrict__ Wg,
                                                   const float* __restrict__ bg,
                                                   const float* __restrict__ Aw,
                                                   const float* __restrict__ Wi,
                                                   const float* __restrict__ Wo,
                                                   unsigned short* __restrict__ xb,
                                                   unsigned short* __restrict__ wib,
                                                   unsigned short* __restrict__ wob,
                                                   float* __restrict__ meta) {
  const int b = blockIdx.x;
  if (b >= BSz) {
    // weight conversion: 8192 blocks x 256 thr x 1 float4 over 2 x 1M float4
    const int n4 = Fdim * Ddim / 4;                    // 1M per tensor
    int i = (b - BSz) * 256 + threadIdx.x;             // 0 .. 2n4-1
    const float* src = (i < n4) ? Wi : Wo;
    unsigned short* dst = (i < n4) ? wib : wob;
    if (i >= n4) i -= n4;
    float4 v = ((const float4*)src)[i];
    ushort4 o;
    o.x = f2bf(v.x); o.y = f2bf(v.y); o.z = f2bf(v.z); o.w = f2bf(v.w);
    ((ushort4*)dst)[i] = o;
    return;
  }
  // ---- router + cvt(x) for token t = b ----
  __shared__ float xs[Ddim];
  __shared__ float dots[Edim + Edim * Rdim];
  const int t = b;
  {
    const int i = threadIdx.x;                         // 256 thr x float4 = 1024
    float4 v = ((const float4*)(x + (size_t)t * Ddim))[i];
    ((float4*)xs)[i] = v;
    ushort4 o;
    o.x = f2bf(v.x); o.y = f2bf(v.y); o.z = f2bf(v.z); o.w = f2bf(v.w);
    ((ushort4*)(xb + (size_t)t * Ddim))[i] = o;
  }
  __syncthreads();
  const int wave = threadIdx.x >> 6, lane = threadIdx.x & 63;
  for (int d = wave * 5; d < wave * 5 + 5; ++d) {
    const float* wrow = (d < Edim) ? (Wg + (size_t)d * Ddim)
                                   : (Aw + (size_t)(d - Edim) * Ddim);
    float s = 0.f;
    for (int i = lane; i < Ddim; i += 64) s += xs[i] * wrow[i];
    for (int off = 32; off; off >>= 1) s += __shfl_down(s, off);
    if (lane == 0) dots[d] = s;
  }
  __syncthreads();
  if (threadIdx.x == 0) {
    float p[Edim];
    float m = -1e30f;
    for (int e = 0; e < Edim; ++e) { p[e] = dots[e] + bg[e]; m = fmaxf(m, p[e]); }
    float sum = 0.f;
    for (int e = 0; e < Edim; ++e) { p[e] = expf(p[e] - m); sum += p[e]; }
    const float inv = 1.f / sum;
    for (int e = 0; e < Edim; ++e) p[e] *= inv;
    int e0 = 0;
    for (int e = 1; e < Edim; ++e) if (p[e] > p[e0]) e0 = e;
    int e1 = (e0 == 0) ? 1 : 0;
    for (int e = 0; e < Edim; ++e) if (e != e0 && p[e] > p[e1]) e1 = e;
    float* mt = meta + (size_t)t * 16;
    mt[0] = (float)e0; mt[1] = (float)e1; mt[2] = p[e0]; mt[3] = p[e1];
    for (int r = 0; r < Rdim; ++r) {
      mt[4 + r] = dots[Edim + e0 * Rdim + r];
      mt[8 + r] = dots[Edim + e1 * Rdim + r];
    }
    mt[12] = 0.f; mt[13] = 0.f; mt[14] = 0.f; mt[15] = 0.f;
  }
}

// ---------------- R13-exact NT bf16 GEMM (4 blocks/CU) ----------------
// C[M,N] = A[M,K] rows bm.. * B[N,K]^T rows bn.. over K-slice [kbase,+kslice).
// 128x128 tile, BK=64, 4 waves (2x2), single-buffered 32KB LDS, plain
// __syncthreads. XOR chunk swizzle (chunk ^ row&7) via pre-swizzled global
// source + swizzled ds_read. Measured optimum across 14 structural variants
// (60.7 us/GEMM, ~550 TF).
// EPI==0: fused MoE epilogue -> outg bf16 (LDS repack, coalesced stores);
//         also zeroes zbuf (split-K base for GEMM2) before the K-loop.
// EPI==1: f32 atomicAdd into outf (split-K).
template <int EPI>
__global__ __launch_bounds__(256, 4)
void gemm97(const unsigned short* __restrict__ Ag,
            const unsigned short* __restrict__ Bg,
            int K, int kslice, int Ncols,
            const float* __restrict__ meta,
            const float* __restrict__ B2,
            unsigned short* __restrict__ outg,
            float* __restrict__ outf,
            float* __restrict__ zbuf) {
  constexpr int BK = 64;
  __shared__ __align__(16) unsigned short sA[128 * BK];   // 16 KB
  __shared__ __align__(16) unsigned short sB[128 * BK];   // 16 KB

  const int tid = threadIdx.x;
  const int lane = tid & 63;
  const int wave = tid >> 6;            // 0..3
  const int wr = wave >> 1, wc = wave & 1;
  const int l16 = lane & 15, lhi = lane >> 4;

  // XCD-aware bijective swizzle on the xy grid (nwg per z-slice % 8 == 0)
  const int nwg = gridDim.x * gridDim.y;
  const int lin = blockIdx.y * gridDim.x + blockIdx.x;
  const int cpx = nwg >> 3;
  const int swz = (lin & 7) * cpx + (lin >> 3);
  const int bx = swz % gridDim.x, by = swz / gridDim.x;
  const int bm = by * 128, bn = bx * 128;
  const int kbase = blockIdx.z * kslice;
  const int NT = kslice / BK;

  // fused zero of the split-K accumulation target (GEMM1 only): 1024 blocks
  // x 256 thr x 4 float4 = 16 MB. Stream order puts this before GEMM2.
  if (EPI == 0) {
    const float4 z4 = make_float4(0.f, 0.f, 0.f, 0.f);
#pragma unroll
    for (int zz = 0; zz < 4; ++zz)
      ((float4*)zbuf)[(size_t)lin * 1024 + zz * 256 + tid] = z4;
  }

  f32x4 acc[4][4] = {};

  // staging: LDS dest linear (tid*8 elems); global source chunk pre-swizzled
  // by the involution chunk' = chunk ^ (row&7). Round rr: rows tid/8 + rr*32.
  const int srow = tid >> 3;                                  // 0..31
  const int scol = ((tid & 7) ^ (srow & 7)) * 8;              // swizzled col
  const int ldst = tid * 8;
  const int xr = l16 & 7;                                     // read-side XOR

  for (int kt = 0; kt < NT; ++kt) {
    const int kof = kbase + kt * BK;
#pragma unroll
    for (int rr = 0; rr < 4; ++rr)
      __builtin_amdgcn_global_load_lds(
          (const __attribute__((address_space(1))) void*)(Ag + (size_t)(bm + srow + rr * 32) * K + kof + scol),
          (__attribute__((address_space(3))) void*)(sA + ldst + rr * 2048), 16, 0, 0);
#pragma unroll
    for (int rr = 0; rr < 4; ++rr)
      __builtin_amdgcn_global_load_lds(
          (const __attribute__((address_space(1))) void*)(Bg + (size_t)(bn + srow + rr * 32) * K + kof + scol),
          (__attribute__((address_space(3))) void*)(sB + ldst + rr * 2048), 16, 0, 0);
    __syncthreads();
#pragma unroll
    for (int kk = 0; kk < 2; ++kk) {
      bf16x8 af[4], bfv[4];
#pragma unroll
      for (int i = 0; i < 4; ++i) {
        af[i] = *(const bf16x8*)(sA + (wr * 64 + i * 16 + l16) * BK + (((kk * 4 + lhi) ^ xr) * 8));
        bfv[i] = *(const bf16x8*)(sB + (wc * 64 + i * 16 + l16) * BK + (((kk * 4 + lhi) ^ xr) * 8));
      }
#pragma unroll
      for (int i = 0; i < 4; ++i)
#pragma unroll
        for (int j = 0; j < 4; ++j)
          acc[i][j] = __builtin_amdgcn_mfma_f32_16x16x32_bf16(af[i], bfv[j], acc[i][j], 0, 0, 0);
    }
    __syncthreads();
  }

  if (EPI == 0) {
    // fused MoE epilogue: gv = sum_{e in top2} w_e*relu(acc + <ll_e,B2[e,f,:]>)
    // repack through LDS (sA rows 0..63, sB rows 64..127) -> coalesced stores.
#pragma unroll
    for (int mi = 0; mi < 4; ++mi) {
#pragma unroll
      for (int r = 0; r < 4; ++r) {
        const int rowl = wr * 64 + mi * 16 + lhi * 4 + r;     // 0..127
        const int row = bm + rowl;
        const float* mt = meta + (size_t)row * 16;
        const int e0 = (int)mt[0], e1 = (int)mt[1];
        const float w0 = mt[2], w1 = mt[3];
        const float4 l0 = *(const float4*)(mt + 4);
        const float4 l1 = *(const float4*)(mt + 8);
        unsigned short* trow = (rowl < 64 ? sA + rowl * 128 : sB + (rowl - 64) * 128);
#pragma unroll
        for (int ni = 0; ni < 4; ++ni) {
          const int coll = wc * 64 + ni * 16 + l16;
          const int f = bn + coll;
          const float4 b0 = *(const float4*)(B2 + ((size_t)e0 * Fdim + f) * Rdim);
          const float4 b1 = *(const float4*)(B2 + ((size_t)e1 * Fdim + f) * Rdim);
          const float a = acc[mi][ni][r];
          const float lora0 = l0.x * b0.x + l0.y * b0.y + l0.z * b0.z + l0.w * b0.w;
          const float lora1 = l1.x * b1.x + l1.y * b1.y + l1.z * b1.z + l1.w * b1.w;
          const float gv = w0 * fmaxf(a + lora0, 0.f) + w1 * fmaxf(a + lora1, 0.f);
          trow[coll] = f2bf(gv);
        }
      }
    }
    __syncthreads();
    // coalesced copy: 128 rows x 256B; 16 threads/row x 16B; 8 rounds.
#pragma unroll
    for (int rnd = 0; rnd < 8; ++rnd) {
      const int idx = rnd * 256 + tid;          // 0..2047
      const int rowl = idx >> 4;                // 0..127
      const int chk = idx & 15;                 // 16B chunk
      const unsigned short* src = (rowl < 64 ? sA + rowl * 128 : sB + (rowl - 64) * 128) + chk * 8;
      *(bf16x8*)(outg + (size_t)(bm + rowl) * Fdim + bn + chk * 8) = *(const bf16x8*)src;
    }
  } else {
    // split-K partial: f32 atomic accumulate (16 lanes x 4B = 64B sectors)
#pragma unroll
    for (int mi = 0; mi < 4; ++mi)
#pragma unroll
      for (int ni = 0; ni < 4; ++ni)
#pragma unroll
        for (int r = 0; r < 4; ++r) {
          const int row = bm + wr * 64 + mi * 16 + lhi * 4 + r;
          const int col = bn + wc * 64 + ni * 16 + l16;
          unsafeAtomicAdd(&outf[(size_t)row * Ncols + col], acc[mi][ni][r]);
        }
  }
}

extern "C" void kernel_launch(void* const* d_in, const int* in_sizes, int n_in,
                              void* d_out, int out_size, void* d_ws, size_t ws_size,
                              hipStream_t stream) {
  const float* x  = (const float*)d_in[0];
  const float* Wg = (const float*)d_in[1];
  const float* bg = (const float*)d_in[2];
  const float* Wi = (const float*)d_in[3];
  const float* Wo = (const float*)d_in[4];
  const float* Aw = (const float*)d_in[5];
  const float* B2 = (const float*)d_in[6];
  float* out = (float*)d_out;

  // workspace layout (bf16 as ushort)
  unsigned short* xb  = (unsigned short*)d_ws;                 // [BSz][Ddim]   8 MB
  unsigned short* wib = xb  + (size_t)BSz  * Ddim;             // [Fdim][Ddim]  8 MB
  unsigned short* wob = wib + (size_t)Fdim * Ddim;             // [Ddim][Fdim]  8 MB
  unsigned short* g   = wob + (size_t)Ddim * Fdim;             // [BSz][Fdim]  32 MB
  float* meta = (float*)(g + (size_t)BSz * Fdim);              // [BSz][16]   256 KB

  // prep: router+cvt(x) (4096 blocks) || Wi/Wo conversion (8192 blocks)
  prep_kernel<<<BSz + 2 * (Fdim * Ddim / 4) / 256, 256, 0, stream>>>(
      x, Wg, bg, Aw, Wi, Wo, xb, wib, wob, meta);

  // GEMM1: base = x * Wi^T, fused MoE epilogue -> g (bf16); zeroes out.
  // 128^2 tile, grid 32x32 = 1024 blocks (4/CU), K=1024
  gemm97<0><<<dim3(Fdim / 128, BSz / 128, 1), 256, 0, stream>>>(
      xb, wib, Ddim, Ddim, Fdim, meta, B2, g, nullptr, out);

  // GEMM2: out = g * Wo^T, split-K x2 (slices of 2048 -> 32-tile pipeline),
  // f32 atomics, grid 8x32x2 = 512 blocks (2/CU)
  gemm97<1><<<dim3(Ddim / 128, BSz / 128, 2), 256, 0, stream>>>(
      g, wob, Fdim, Fdim / 2, Ddim, nullptr, nullptr, nullptr, out, nullptr);
}